// Round 6
// baseline (208.062 us; speedup 1.0000x reference)
//
#include <hip/hip_runtime.h>

// SSIM, wave-per-row-strip, software-pipelined, phase-split, DPP halo.
// Each wave owns full image width: 64 lanes x 8 cols = 512. Vertical 11-row
// box sums slide in registers; retiring row re-loaded from global (L2-hot).
// R9: horizontal 11-col halo exchange moves from __shfl (ds_bpermute on the
// per-CU LDS pipe, shared by 4 SIMDs) to whole-wave DPP shifts on the VALU
// pipe: wave_shr:1 (0x138) = value from lane-1, wave_shl:1 (0x130) = value
// from lane+1, bound_ctrl zeroing lane 0 / lane 63 = image-edge zero-pad.
// One v_mov_dpp per halo value, no LDS-pipe traffic, no boundary patches.
// (R8 tried readlane/writelane patches; __builtin_amdgcn_writelane does not
// exist in this clang -- wave_* DPP modes make it unnecessary.)
// Rationale: 50 bpermutes/step x ~18cy on one LDS pipe = 87% (R4) / 100% (R6)
// pipe occupancy -- explains R6's weak 1.15x from 2x waves and R7's null from
// -25% VALU (VALUBusy 29.5->26.4, time flat). VALU has slack (26% busy).

static constexpr int HI = 512, WI = 512;
static constexpr int RS = 16;             // output rows per wave-strip
static constexpr int SPB = HI / RS;       // strips per batch = 32

struct R8 { float4 a, b; };

__device__ __forceinline__ R8 ld8(const float* p) {
  R8 r; r.a = ((const float4*)p)[0]; r.b = ((const float4*)p)[1]; return r;
}

__device__ __forceinline__ void unp(const R8& v, float o[8]) {
  o[0]=v.a.x; o[1]=v.a.y; o[2]=v.a.z; o[3]=v.a.w;
  o[4]=v.b.x; o[5]=v.b.y; o[6]=v.b.z; o[7]=v.b.w;
}

// value from lane-1 across whole wave; lane 0 -> 0   (v_mov_dpp wave_shr:1)
__device__ __forceinline__ float shr1(float x) {
  return __int_as_float(__builtin_amdgcn_update_dpp(
      0, __float_as_int(x), 0x138, 0xf, 0xf, true));
}
// value from lane+1 across whole wave; lane 63 -> 0  (v_mov_dpp wave_shl:1)
__device__ __forceinline__ float shl1(float x) {
  return __int_as_float(__builtin_amdgcn_update_dpp(
      0, __float_as_int(x), 0x130, 0xf, 0xf, true));
}

__device__ __forceinline__ void horiz11(const float v[8], float H[8]) {
  float L[5], R[5];
#pragma unroll
  for (int k = 0; k < 5; ++k) {
    L[k] = shr1(v[3 + k]);   // image cols -5..-1 zero-pad (lane0 bound_ctrl)
    R[k] = shl1(v[k]);       // image cols 512..516 zero-pad (lane63)
  }
  float h = (((L[0] + L[1]) + (L[2] + L[3])) + ((L[4] + v[0]) + (v[1] + v[2])))
            + ((v[3] + v[4]) + v[5]);
  H[0] = h;
  h = h - L[0] + v[6]; H[1] = h;
  h = h - L[1] + v[7]; H[2] = h;
  h = h - L[2] + R[0]; H[3] = h;
  h = h - L[3] + R[1]; H[4] = h;
  h = h - L[4] + R[2]; H[5] = h;
  h = h - v[0] + R[3]; H[6] = h;
  h = h - v[1] + R[4]; H[7] = h;
}

__global__ __launch_bounds__(256, 2)
void ssim_wave(const float* __restrict__ img, const float* __restrict__ ref,
               const float* __restrict__ drng, const float* __restrict__ zrow,
               float* __restrict__ out)
{
  // Bijective XCD swizzle (512 blocks % 8 == 0): adjacent strips share 10
  // halo rows -> keep them on the same per-XCD L2.
  int bid = (int)blockIdx.x;
  const int nb = (int)gridDim.x;
  if ((nb & 7) == 0) {
    const int cpx = nb >> 3;
    bid = (bid & 7) * cpx + (bid >> 3);
  }

  const int lane = threadIdx.x & 63;
  const int wv   = bid * 4 + (threadIdx.x >> 6);
  const int b    = wv / SPB;
  const int r0   = (wv % SPB) * RS;
  const int c0   = lane * 8;

  const float dr  = drng[b];
  const float C1  = (0.01f * dr) * (0.01f * dr);
  const float C2  = (0.03f * dr) * (0.03f * dr);
  const float inv_n    = 1.0f / 121.0f;
  const float cov_norm = 121.0f / 120.0f;

  const size_t base = (size_t)b * ((size_t)HI * WI);
  const float* xb = img + base;
  const float* yb = ref + base;
  float*       ob = out + base;

  // wave-uniform pointer selects; OOB -> dummy zero row (branch-free loads)
  auto nrow = [&](const float* tb, int t) -> const float* {
    const int r = r0 - 5 + t;
    return (((unsigned)r < (unsigned)HI) ? tb + (size_t)r * WI : zrow) + c0;
  };
  auto orow = [&](const float* tb, int t) -> const float* {   // only t>=11
    const int r = r0 - 16 + t;
    return (((unsigned)r < (unsigned)HI) ? tb + (size_t)r * WI : zrow) + c0;
  };

  float Sx[8], Sy[8], Sxx[8], Syy[8], Sxy[8];
#pragma unroll
  for (int c = 0; c < 8; ++c) { Sx[c]=0.f; Sy[c]=0.f; Sxx[c]=0.f; Syy[c]=0.f; Sxy[c]=0.f; }

  auto accA = [&](const float xn[8], const float yn[8]) {
#pragma unroll
    for (int c = 0; c < 8; ++c) {
      Sx[c] += xn[c];  Sy[c] += yn[c];
      Sxx[c] = fmaf(xn[c], xn[c], Sxx[c]);
      Syy[c] = fmaf(yn[c], yn[c], Syy[c]);
      Sxy[c] = fmaf(xn[c], yn[c], Sxy[c]);
    }
  };
  auto accB = [&](const float xn[8], const float yn[8],
                  const float xo[8], const float yo[8]) {
#pragma unroll
    for (int c = 0; c < 8; ++c) {
      Sx[c] += xn[c] - xo[c];
      Sy[c] += yn[c] - yo[c];
      Sxx[c] = fmaf(xn[c], xn[c], fmaf(-xo[c], xo[c], Sxx[c]));
      Syy[c] = fmaf(yn[c], yn[c], fmaf(-yo[c], yo[c], Syy[c]));
      Sxy[c] = fmaf(xn[c], yn[c], fmaf(-xo[c], yo[c], Sxy[c]));
    }
  };

  auto emit = [&](int t) {   // output row r0 + t - 10
    float H0[8], H1[8], H2[8], H3[8], H4[8];
    horiz11(Sx,  H0);
    horiz11(Sy,  H1);
    horiz11(Sxx, H2);
    horiz11(Syy, H3);
    horiz11(Sxy, H4);
    float res[8];
#pragma unroll
    for (int c = 0; c < 8; ++c) {
      const float ux  = H0[c] * inv_n, uy  = H1[c] * inv_n;
      const float uxx = H2[c] * inv_n, uyy = H3[c] * inv_n, uxy = H4[c] * inv_n;
      const float vx  = cov_norm * (uxx - ux * ux);
      const float vy  = cov_norm * (uyy - uy * uy);
      const float vxy = cov_norm * (uxy - ux * uy);
      const float A1 = 2.f * ux * uy + C1;
      const float A2 = 2.f * vxy + C2;
      const float B1 = ux * ux + uy * uy + C1;
      const float B2 = vx + vy + C2;
      res[c] = (A1 * A2) * __builtin_amdgcn_rcpf(B1 * B2);
    }
    const int ro = r0 + t - 10;
    float4* po = (float4*)(ob + (size_t)ro * WI + c0);
    po[0] = make_float4(res[0], res[1], res[2], res[3]);
    po[1] = make_float4(res[4], res[5], res[6], res[7]);
  };

  // depth-2 pipeline slots; slot parity = t & 1 (compile-time per body below)
  R8 nx[2], ny[2], ox[2], oy[2];
  nx[0] = ld8(nrow(xb, 0)); ny[0] = ld8(nrow(yb, 0));
  nx[1] = ld8(nrow(xb, 1)); ny[1] = ld8(nrow(yb, 1));

  // ---- Phase A: t = 0..8 — new streams only, add-only accumulate ----
#pragma unroll 2
  for (int t = 0; t < 9; ++t) {
    const int s = t & 1;
    float xn[8], yn[8];
    unp(nx[s], xn); unp(ny[s], yn);
    nx[s] = ld8(nrow(xb, t + 2)); ny[s] = ld8(nrow(yb, t + 2));
    accA(xn, yn);
  }
  // ---- t = 9: start old-stream pipeline (for t=11) ----
  {
    float xn[8], yn[8];
    unp(nx[1], xn); unp(ny[1], yn);
    nx[1] = ld8(nrow(xb, 11)); ny[1] = ld8(nrow(yb, 11));
    ox[1] = ld8(orow(xb, 11)); oy[1] = ld8(orow(yb, 11));
    accA(xn, yn);
  }
  // ---- t = 10: window full, first output ----
  {
    float xn[8], yn[8];
    unp(nx[0], xn); unp(ny[0], yn);
    nx[0] = ld8(nrow(xb, 12)); ny[0] = ld8(nrow(yb, 12));
    ox[0] = ld8(orow(xb, 12)); oy[0] = ld8(orow(yb, 12));
    accA(xn, yn);
    emit(10);
  }

  // ---- Phase B: t = 11..25 — full slide + output every step ----
  auto stepB = [&](int t, int s, bool issue) {
    float xn[8], yn[8], xo[8], yo[8];
    unp(nx[s], xn); unp(ny[s], yn); unp(ox[s], xo); unp(oy[s], yo);
    if (issue) {
      nx[s] = ld8(nrow(xb, t + 2)); ny[s] = ld8(nrow(yb, t + 2));
      ox[s] = ld8(orow(xb, t + 2)); oy[s] = ld8(orow(yb, t + 2));
    }
    accB(xn, yn, xo, yo);
    emit(t);
  };

#pragma unroll 1
  for (int u = 0; u < 6; ++u) {        // t = 11..22, slot parity (1,0)
    stepB(11 + 2 * u, 1, true);
    stepB(12 + 2 * u, 0, true);
  }
  stepB(23, 1, true);                  // issues t=25
  stepB(24, 0, false);
  stepB(25, 1, false);
}

extern "C" void kernel_launch(void* const* d_in, const int* in_sizes, int n_in,
                              void* d_out, int out_size, void* d_ws, size_t ws_size,
                              hipStream_t stream)
{
  const float* img = (const float*)d_in[0];
  const float* ref = (const float*)d_in[1];
  const float* drg = (const float*)d_in[2];
  float* out = (float*)d_out;

  // zero dummy row (d_ws is re-poisoned to 0xAA before every launch)
  (void)hipMemsetAsync(d_ws, 0, (size_t)WI * sizeof(float) + 64, stream);

  const int B = in_sizes[0] / (HI * WI);          // 64
  const int waves = B * SPB;                      // 2048
  dim3 grid(waves / 4);                           // 512 blocks, 4 waves each
  dim3 block(256);
  hipLaunchKernelGGL(ssim_wave, grid, block, 0, stream,
                     img, ref, drg, (const float*)d_ws, out);
}